// Round 16
// baseline (301.122 us; speedup 1.0000x reference)
//
#include <hip/hip_runtime.h>
#include <stdint.h>

#define S_ 512
#define B_ 64
#define V_ 50000
#define E_ 300
#define H_ 256
#define C_ 5

typedef _Float16 h8_t __attribute__((ext_vector_type(8)));
typedef float f32x4 __attribute__((ext_vector_type(4)));

// tanh(x) = 1 - 2/(e^{2x}+1); e^{2x}=2^{2x*log2e}.
__device__ __forceinline__ float fast_tanh(float x) {
    float e = __builtin_amdgcn_exp2f(x * 2.88539008177793f);  // 2*log2(e)
    return fmaf(-2.0f, __builtin_amdgcn_rcpf(e + 1.0f), 1.0f);
}

// Consumer gate: wait until all 64 producer blocks of 64-step group grp have
// released, then acquire-fence (cross-XCD visibility). Only 8 gates total ->
// fence vmcnt-drain cost is negligible (R10's per-8-step gating had 64).
__device__ __forceinline__ void wait_group(volatile unsigned* gcnt, int grp) {
    while (__hip_atomic_load((const unsigned*)&gcnt[grp], __ATOMIC_RELAXED,
                             __HIP_MEMORY_SCOPE_AGENT) != 64u) {
        __builtin_amdgcn_s_sleep(16);
    }
    __builtin_amdgcn_fence(__ATOMIC_ACQUIRE, "agent");
}

// ---------------------------------------------------------------------------
// Kernel A: pack W_ih (H,E) f32 -> WB f16 in B-fragment order for the xw GEMM.
// ---------------------------------------------------------------------------
__global__ void wb_prep_kernel(const float* __restrict__ W_ih,
                               uint4* __restrict__ WB) {
    int g = blockIdx.x * 256 + threadIdx.x;  // 0 .. 16*10*64-1
    if (g >= 16 * 10 * 64) return;
    int l = g & 63;
    int ks = (g >> 6) % 10;
    int nt = g / 640;
    int h = nt * 16 + (l & 15);
    int e0 = ks * 32 + (l >> 4) * 8;
    h8_t v;
#pragma unroll
    for (int j = 0; j < 8; ++j) {
        int e = e0 + j;
        v[j] = (e < E_) ? (_Float16)W_ih[(size_t)h * E_ + e] : (_Float16)0.0f;
    }
    WB[g] = __builtin_bit_cast(uint4, v);
}

// ---------------------------------------------------------------------------
// FUSED producer-consumer kernel. Grid = 520 blocks x 512 threads.
//   blocks 0..7   : rnn consumer (R14 broadcast-8 + split-epilogue, 231us)
//   blocks 8..519 : xw producer; block 8+g computes xw for timestep s=g.
// Gating at 64-STEP granularity (8 groups of 64 producer blocks):
//   producer: stores -> __syncthreads (drains vmcnt) -> tid0 __threadfence
//             -> atomicAdd(gcnt[g>>6], 1)
//   consumer: wait_group before first use of each group (8 acquire fences
//             total; R10's failure was 64 of them draining the prefetch
//             stream every 8 steps).
// Timeline: 8 consumers dispatched first (8 CUs); 512 producers flood the
// other 248 CUs (2 co-resident each) -> group 0 ready ~12us, all xw done
// ~15us; consumer burns 64 steps per ~29us -> gate waits only at group 0.
// ---------------------------------------------------------------------------
__global__ __launch_bounds__(512, 2) void fused_kernel(
    const int* __restrict__ idx, const float* __restrict__ emb,
    const uint4* __restrict__ WB, const float* __restrict__ b_ih,
    const float* __restrict__ b_hh, float* __restrict__ xw,
    const float* __restrict__ W_hh, float* __restrict__ hsum_out,
    unsigned* __restrict__ gcnt) {
    __shared__ __attribute__((aligned(16))) unsigned char smem[40960];
    const int tid = threadIdx.x;

    if (blockIdx.x >= 8) {
        // ================= xw producer (R7 structure) =================
        const int g = blockIdx.x - 8;  // timestep this block produces
        uint4* Afrag = (uint4*)smem;   // 4*10*64 uint4 = 40 KB
        const int w = tid >> 6;
        const int l = tid & 63;
        const int n = l & 15;
        const int hi = l >> 4;
        const int base = g * 64;

        for (int cc = tid; cc < 64 * 40; cc += 512) {
            int m = cc / 40;
            int c = cc - m * 40;  // chunk: e = 8c..8c+7
            int ks = c >> 2;
            int hic = c & 3;
            const float* src = emb + (size_t)idx[base + m] * E_ + 8 * c;
            h8_t v;
            if (c < 37) {
                float4 f0 = *(const float4*)src;
                float4 f1 = *(const float4*)(src + 4);
                v[0] = (_Float16)f0.x; v[1] = (_Float16)f0.y;
                v[2] = (_Float16)f0.z; v[3] = (_Float16)f0.w;
                v[4] = (_Float16)f1.x; v[5] = (_Float16)f1.y;
                v[6] = (_Float16)f1.z; v[7] = (_Float16)f1.w;
            } else if (c == 37) {
                float4 f0 = *(const float4*)src;
                v[0] = (_Float16)f0.x; v[1] = (_Float16)f0.y;
                v[2] = (_Float16)f0.z; v[3] = (_Float16)f0.w;
                v[4] = (_Float16)0.0f; v[5] = (_Float16)0.0f;
                v[6] = (_Float16)0.0f; v[7] = (_Float16)0.0f;
            } else {
                v = (h8_t)(_Float16)0.0f;
            }
            int fl = (hic << 4) | (m & 15);
            int mt = m >> 4;
            Afrag[(mt * 10 + ks) * 64 + fl] = __builtin_bit_cast(uint4, v);
        }
        __syncthreads();

        float bias0 = b_ih[w * 32 + n] + b_hh[w * 32 + n];
        float bias1 = b_ih[w * 32 + 16 + n] + b_hh[w * 32 + 16 + n];
        f32x4 c[4][2];
#pragma unroll
        for (int mt = 0; mt < 4; ++mt) {
            c[mt][0] = (f32x4)bias0;
            c[mt][1] = (f32x4)bias1;
        }

        const uint4* wb0 = WB + ((2 * w) * 10) * 64 + l;
        const uint4* wb1 = WB + ((2 * w + 1) * 10) * 64 + l;
#pragma unroll
        for (int ks = 0; ks < 10; ++ks) {
            h8_t b0 = __builtin_bit_cast(h8_t, wb0[ks * 64]);
            h8_t b1 = __builtin_bit_cast(h8_t, wb1[ks * 64]);
#pragma unroll
            for (int mt = 0; mt < 4; ++mt) {
                h8_t a =
                    __builtin_bit_cast(h8_t, Afrag[(mt * 10 + ks) * 64 + l]);
                c[mt][0] = __builtin_amdgcn_mfma_f32_16x16x32_f16(
                    a, b0, c[mt][0], 0, 0, 0);
                c[mt][1] = __builtin_amdgcn_mfma_f32_16x16x32_f16(
                    a, b1, c[mt][1], 0, 0, 0);
            }
        }

#pragma unroll
        for (int mt = 0; mt < 4; ++mt)
#pragma unroll
            for (int q = 0; q < 2; ++q) {
                float* op = xw + (size_t)(base + mt * 16 + hi * 4) * H_ +
                            w * 32 + q * 16 + n;
#pragma unroll
                for (int r = 0; r < 4; ++r) op[(size_t)r * H_] = c[mt][q][r];
            }

        // release: all block stores done -> L2 flush -> signal group
        __syncthreads();
        if (tid == 0) {
            __threadfence();
            atomicAdd(&gcnt[g >> 6], 1u);
        }
        return;
    }

    // ========== rnn consumer (R14: broadcast-8 + split epilogue) ==========
    const int w = tid >> 6;  // wave 0..7, rows 32w..32w+31
    const int l = tid & 63;
    const int n = l & 15;    // A row / B col / C col (0..15)
    const int hi = l >> 4;   // k-group
    const int col = n & 7;   // real batch col within block
    const int sel = n >> 3;  // epilogue tile handled by this lane (0 or 1)
    const int bbase = blockIdx.x * 8;
    const int rowbase = w * 32;

    char* lds = (char*)smem;  // [2][4096] H double-buffer

    // ---- A fragments: W_hh rows rowbase..rowbase+31 as f16 (64 regs) ----
    h8_t a[2][8];
#pragma unroll
    for (int mt = 0; mt < 2; ++mt) {
        const float* wr = W_hh + (size_t)(rowbase + mt * 16 + n) * H_;
#pragma unroll
        for (int ks = 0; ks < 8; ++ks) {
            const float* wp = wr + ks * 32 + hi * 8;
            float4 f0 = *(const float4*)wp;
            float4 f1 = *(const float4*)(wp + 4);
            h8_t v;
            v[0] = (_Float16)f0.x; v[1] = (_Float16)f0.y;
            v[2] = (_Float16)f0.z; v[3] = (_Float16)f0.w;
            v[4] = (_Float16)f1.x; v[5] = (_Float16)f1.y;
            v[6] = (_Float16)f1.z; v[7] = (_Float16)f1.w;
            a[mt][ks] = v;
        }
    }

    // H'-write byte offset (buffer-relative): tile sel, rows k0..k0+3, col
    const int wboff =
        (w * 4 + sel * 2 + (hi >> 1)) * 128 + col * 16 + (hi & 1) * 8;
    // B-read base (buffer-relative); full addr: CUR*4096 + rdbase + ks*512
    const int rdbase = hi * 128 + col * 16;

    // zero H buffer 0 (4 KB = 1024 dwords)
    for (int t = tid; t < 1024; t += 512) ((unsigned int*)lds)[t] = 0u;

    f32x4 hs = (f32x4)0.0f;  // running sum for this lane's tile (sel)

    // gate group 0 (steps 0..63) before first xw reads
    wait_group(gcnt, 0);

    // per-lane xw base: xw[s][bbase+col][rowbase + mt*16 + hi*4 + r]
    const float* xwl = xw + (size_t)(bbase + col) * H_ + rowbase + hi * 4;
    // 4-slot rotation of xw-as-C-operand buffers (distance-2 prefetch)
    f32x4 cv[4][2];
    cv[0][0] = *(const f32x4*)(xwl);                  // s = 0
    cv[0][1] = *(const f32x4*)(xwl + 16);
    cv[1][0] = *(const f32x4*)(xwl + 16384);          // s = 1
    cv[1][1] = *(const f32x4*)(xwl + 16384 + 16);
    __syncthreads();  // zero-init visible

#define STEP(CUR, I, SBASE)                                                    \
    {                                                                          \
        int sp = (SBASE) + 2;                                                  \
        if (sp < S_ && (sp & 63) == 0) wait_group(gcnt, sp >> 6);              \
        if (sp > S_ - 1) sp = S_ - 1;                                          \
        cv[(I + 2) & 3][0] = *(const f32x4*)(xwl + (size_t)sp * 16384);        \
        cv[(I + 2) & 3][1] = *(const f32x4*)(xwl + (size_t)sp * 16384 + 16);   \
        h8_t bf[8];                                                            \
        _Pragma("unroll") for (int ks = 0; ks < 8; ++ks)                       \
            bf[ks] = *(const h8_t*)(lds + (CUR)*4096 + rdbase + ks * 512);     \
        _Pragma("unroll") for (int ks = 0; ks < 8; ++ks) {                     \
            cv[I][0] = __builtin_amdgcn_mfma_f32_16x16x32_f16(                 \
                a[0][ks], bf[ks], cv[I][0], 0, 0, 0);                          \
            cv[I][1] = __builtin_amdgcn_mfma_f32_16x16x32_f16(                 \
                a[1][ks], bf[ks], cv[I][1], 0, 0, 0);                          \
        }                                                                      \
        {                                                                      \
            f32x4 sv = (sel == 0) ? cv[I][0] : cv[I][1];                       \
            float h0 = fast_tanh(sv[0]);                                       \
            float h1 = fast_tanh(sv[1]);                                       \
            float h2 = fast_tanh(sv[2]);                                       \
            float h3 = fast_tanh(sv[3]);                                       \
            hs[0] += h0; hs[1] += h1; hs[2] += h2; hs[3] += h3;                \
            uint2 pk;                                                          \
            pk.x = __builtin_bit_cast(unsigned int,                            \
                                      __builtin_amdgcn_cvt_pkrtz(h0, h1));     \
            pk.y = __builtin_bit_cast(unsigned int,                            \
                                      __builtin_amdgcn_cvt_pkrtz(h2, h3));     \
            *(uint2*)(lds + ((CUR) ^ 1) * 4096 + wboff) = pk;                  \
        }                                                                      \
        asm volatile("s_waitcnt lgkmcnt(0)" ::: "memory");                     \
        __builtin_amdgcn_s_barrier();                                          \
    }

    for (int s = 0; s < S_; s += 4) {
        STEP(0, 0, s)
        STEP(1, 1, s + 1)
        STEP(0, 2, s + 2)
        STEP(1, 3, s + 3)
    }
#undef STEP

    // lane writes its tile's rows: rowbase + sel*16 + hi*4 .. +3, col
    {
        float4 o;
        o.x = hs[0]; o.y = hs[1]; o.z = hs[2]; o.w = hs[3];
        *(float4*)(hsum_out + (size_t)(bbase + col) * H_ + rowbase + sel * 16 +
                   hi * 4) = o;
    }
}

// ---------------------------------------------------------------------------
// Kernel D: summed logits = hsum @ W_out^T + S*b_out, then log_softmax.
// ---------------------------------------------------------------------------
__global__ void out_kernel(const float* __restrict__ hsum,
                           const float* __restrict__ W_out,
                           const float* __restrict__ b_out,
                           float* __restrict__ out) {
    int b = threadIdx.x;
    if (b >= B_) return;
    float logits[C_];
#pragma unroll
    for (int c = 0; c < C_; ++c) {
        float acc = 0.0f;
        for (int k = 0; k < H_; ++k)
            acc = fmaf(hsum[b * H_ + k], W_out[c * H_ + k], acc);
        logits[c] = acc + (float)S_ * b_out[c];
    }
    float m = logits[0];
#pragma unroll
    for (int c = 1; c < C_; ++c) m = fmaxf(m, logits[c]);
    float sum = 0.0f;
#pragma unroll
    for (int c = 0; c < C_; ++c) sum += expf(logits[c] - m);
    float lse = logf(sum);
#pragma unroll
    for (int c = 0; c < C_; ++c) out[b * C_ + c] = logits[c] - m - lse;
}

// ---------------------------------------------------------------------------
extern "C" void kernel_launch(void* const* d_in, const int* in_sizes, int n_in,
                              void* d_out, int out_size, void* d_ws,
                              size_t ws_size, hipStream_t stream) {
    const int* idx = (const int*)d_in[0];
    const float* emb = (const float*)d_in[1];
    const float* W_ih = (const float*)d_in[2];
    const float* W_hh = (const float*)d_in[3];
    const float* b_ih = (const float*)d_in[4];
    const float* b_hh = (const float*)d_in[5];
    const float* W_out = (const float*)d_in[6];
    const float* b_out = (const float*)d_in[7];
    float* out = (float*)d_out;

    float* ws = (float*)d_ws;
    uint4* WB = (uint4*)ws;                        // 16*10*64 uint4 = 160 KB
    float* xw = ws + 40960;                        // S*B*H floats
    float* hsum = xw + (size_t)S_ * B_ * H_;       // B*H floats
    unsigned* gcnt = (unsigned*)(hsum + B_ * H_);  // 8 u32 group counters

    hipMemsetAsync(gcnt, 0, 8 * sizeof(unsigned), stream);
    hipLaunchKernelGGL(wb_prep_kernel, dim3(40), dim3(256), 0, stream, W_ih,
                       WB);
    hipLaunchKernelGGL(fused_kernel, dim3(520), dim3(512), 0, stream, idx, emb,
                       WB, b_ih, b_hh, xw, W_hh, hsum, gcnt);
    hipLaunchKernelGGL(out_kernel, dim3(1), dim3(64), 0, stream, hsum, W_out,
                       b_out, out);
}

// Round 17
// 283.397 us; speedup vs baseline: 1.0625x; 1.0625x over previous
//
#include <hip/hip_runtime.h>
#include <stdint.h>

#define S_ 512
#define B_ 64
#define V_ 50000
#define E_ 300
#define H_ 256
#define C_ 5
#define NPROD 248  // producer blocks; block 8+p produces steps p, p+248, p+496

typedef _Float16 h8_t __attribute__((ext_vector_type(8)));
typedef float f32x4 __attribute__((ext_vector_type(4)));

// tanh(x) = 1 - 2/(e^{2x}+1); e^{2x}=2^{2x*log2e}.
__device__ __forceinline__ float fast_tanh(float x) {
    float e = __builtin_amdgcn_exp2f(x * 2.88539008177793f);  // 2*log2(e)
    return fmaf(-2.0f, __builtin_amdgcn_rcpf(e + 1.0f), 1.0f);
}

// Consumer gate: all 64 steps of 64-step group grp released -> acquire fence.
// Only 8 gates total (R10's per-8-step fencing was the regression).
__device__ __forceinline__ void wait_group(unsigned* gcnt, int grp) {
    while (__hip_atomic_load(&gcnt[grp], __ATOMIC_RELAXED,
                             __HIP_MEMORY_SCOPE_AGENT) != 64u) {
        __builtin_amdgcn_s_sleep(16);
    }
    __builtin_amdgcn_fence(__ATOMIC_ACQUIRE, "agent");
}

// B-fragment of W_ih for the xw GEMM, loaded directly from f32 (no prep
// kernel): lane (n,hi) of frag (h = base row + n, e0 = ks*32 + hi*8).
__device__ __forceinline__ h8_t load_wfrag(const float* __restrict__ W,
                                           int h, int e0) {
    h8_t v;
    if (e0 + 8 <= E_) {
        float4 f0 = *(const float4*)(W + (size_t)h * E_ + e0);
        float4 f1 = *(const float4*)(W + (size_t)h * E_ + e0 + 4);
        v[0] = (_Float16)f0.x; v[1] = (_Float16)f0.y;
        v[2] = (_Float16)f0.z; v[3] = (_Float16)f0.w;
        v[4] = (_Float16)f1.x; v[5] = (_Float16)f1.y;
        v[6] = (_Float16)f1.z; v[7] = (_Float16)f1.w;
    } else if (e0 < E_) {  // e0 = 296: last 4 real + 4 pad
        float4 f0 = *(const float4*)(W + (size_t)h * E_ + e0);
        v[0] = (_Float16)f0.x; v[1] = (_Float16)f0.y;
        v[2] = (_Float16)f0.z; v[3] = (_Float16)f0.w;
        v[4] = (_Float16)0.0f; v[5] = (_Float16)0.0f;
        v[6] = (_Float16)0.0f; v[7] = (_Float16)0.0f;
    } else {
        v = (h8_t)(_Float16)0.0f;
    }
    return v;
}

// ---------------------------------------------------------------------------
// FUSED kernel. Grid = 256 blocks x 512 threads (<= 2 blocks/CU -> producers
// spread across CUs, near-zero contention with the 8 consumer blocks).
//   blocks 0..7   : rnn consumer (R14 broadcast-8 + split-epilogue, 232us)
//                   + fused logits/log_softmax epilogue (hsum is block-local)
//   blocks 8..255 : xw producer p = blockIdx.x-8, steps {p, p+248, p+496}
// Producer releases per step: stores -> __syncthreads (vmcnt drained) ->
// tid0 __threadfence -> atomicAdd(gcnt[s>>6]). Consumer gates once per
// 64-step group (8 acquire fences total).
// ---------------------------------------------------------------------------
__global__ __launch_bounds__(512, 2) void fused_kernel(
    const int* __restrict__ idx, const float* __restrict__ emb,
    const float* __restrict__ W_ih, const float* __restrict__ b_ih,
    const float* __restrict__ b_hh, float* __restrict__ xw,
    const float* __restrict__ W_hh, const float* __restrict__ W_out,
    const float* __restrict__ b_out, float* __restrict__ out,
    unsigned* __restrict__ gcnt) {
    __shared__ __attribute__((aligned(16))) unsigned char smem[40960];
    const int tid = threadIdx.x;

    if (blockIdx.x >= 8) {
        // ================= xw producer =================
        const int p = blockIdx.x - 8;
        uint4* Afrag = (uint4*)smem;  // 4*10*64 uint4 = 40 KB
        const int w = tid >> 6;
        const int l = tid & 63;
        const int n = l & 15;
        const int hi = l >> 4;

        // W_ih B-fragments for this wave's 32 cols (loop-invariant): 80 regs
        h8_t bw0[10], bw1[10];
#pragma unroll
        for (int ks = 0; ks < 10; ++ks) {
            bw0[ks] = load_wfrag(W_ih, (2 * w) * 16 + n, ks * 32 + hi * 8);
            bw1[ks] = load_wfrag(W_ih, (2 * w + 1) * 16 + n, ks * 32 + hi * 8);
        }
        const float bias0 = b_ih[w * 32 + n] + b_hh[w * 32 + n];
        const float bias1 = b_ih[w * 32 + 16 + n] + b_hh[w * 32 + 16 + n];

        for (int s = p; s < S_; s += NPROD) {
            const int base = s * 64;
            __syncthreads();  // Afrag free (prev step's readers done)
            for (int cc = tid; cc < 64 * 40; cc += 512) {
                int m = cc / 40;
                int c = cc - m * 40;  // chunk: e = 8c..8c+7
                int ks = c >> 2;
                int hic = c & 3;
                const float* src = emb + (size_t)idx[base + m] * E_ + 8 * c;
                h8_t v;
                if (c < 37) {
                    float4 f0 = *(const float4*)src;
                    float4 f1 = *(const float4*)(src + 4);
                    v[0] = (_Float16)f0.x; v[1] = (_Float16)f0.y;
                    v[2] = (_Float16)f0.z; v[3] = (_Float16)f0.w;
                    v[4] = (_Float16)f1.x; v[5] = (_Float16)f1.y;
                    v[6] = (_Float16)f1.z; v[7] = (_Float16)f1.w;
                } else if (c == 37) {
                    float4 f0 = *(const float4*)src;
                    v[0] = (_Float16)f0.x; v[1] = (_Float16)f0.y;
                    v[2] = (_Float16)f0.z; v[3] = (_Float16)f0.w;
                    v[4] = (_Float16)0.0f; v[5] = (_Float16)0.0f;
                    v[6] = (_Float16)0.0f; v[7] = (_Float16)0.0f;
                } else {
                    v = (h8_t)(_Float16)0.0f;
                }
                int fl = (hic << 4) | (m & 15);
                int mt = m >> 4;
                Afrag[(mt * 10 + ks) * 64 + fl] = __builtin_bit_cast(uint4, v);
            }
            __syncthreads();

            f32x4 c[4][2];
#pragma unroll
            for (int mt = 0; mt < 4; ++mt) {
                c[mt][0] = (f32x4)bias0;
                c[mt][1] = (f32x4)bias1;
            }
#pragma unroll
            for (int ks = 0; ks < 10; ++ks) {
#pragma unroll
                for (int mt = 0; mt < 4; ++mt) {
                    h8_t a = __builtin_bit_cast(h8_t,
                                                Afrag[(mt * 10 + ks) * 64 + l]);
                    c[mt][0] = __builtin_amdgcn_mfma_f32_16x16x32_f16(
                        a, bw0[ks], c[mt][0], 0, 0, 0);
                    c[mt][1] = __builtin_amdgcn_mfma_f32_16x16x32_f16(
                        a, bw1[ks], c[mt][1], 0, 0, 0);
                }
            }
#pragma unroll
            for (int mt = 0; mt < 4; ++mt)
#pragma unroll
                for (int q = 0; q < 2; ++q) {
                    float* op = xw + (size_t)(base + mt * 16 + hi * 4) * H_ +
                                w * 32 + q * 16 + n;
#pragma unroll
                    for (int r = 0; r < 4; ++r)
                        op[(size_t)r * H_] = c[mt][q][r];
                }

            __syncthreads();  // all block stores complete (vmcnt drained)
            if (tid == 0) {
                __threadfence();
                atomicAdd(&gcnt[s >> 6], 1u);
            }
        }
        return;
    }

    // ========== rnn consumer (R14: broadcast-8 + split epilogue) ==========
    const int w = tid >> 6;  // wave 0..7, rows 32w..32w+31
    const int l = tid & 63;
    const int n = l & 15;    // A row / B col / C col (0..15)
    const int hi = l >> 4;   // k-group
    const int col = n & 7;   // real batch col within block
    const int sel = n >> 3;  // epilogue tile handled by this lane (0 or 1)
    const int bbase = blockIdx.x * 8;
    const int rowbase = w * 32;

    char* lds = (char*)smem;  // [2][4096] H double-buffer

    // ---- A fragments: W_hh rows rowbase..rowbase+31 as f16 (64 regs) ----
    h8_t a[2][8];
#pragma unroll
    for (int mt = 0; mt < 2; ++mt) {
        const float* wr = W_hh + (size_t)(rowbase + mt * 16 + n) * H_;
#pragma unroll
        for (int ks = 0; ks < 8; ++ks) {
            const float* wp = wr + ks * 32 + hi * 8;
            float4 f0 = *(const float4*)wp;
            float4 f1 = *(const float4*)(wp + 4);
            h8_t v;
            v[0] = (_Float16)f0.x; v[1] = (_Float16)f0.y;
            v[2] = (_Float16)f0.z; v[3] = (_Float16)f0.w;
            v[4] = (_Float16)f1.x; v[5] = (_Float16)f1.y;
            v[6] = (_Float16)f1.z; v[7] = (_Float16)f1.w;
            a[mt][ks] = v;
        }
    }

    // H'-write byte offset (buffer-relative): tile sel, rows k0..k0+3, col
    const int wboff =
        (w * 4 + sel * 2 + (hi >> 1)) * 128 + col * 16 + (hi & 1) * 8;
    // B-read base (buffer-relative); full addr: CUR*4096 + rdbase + ks*512
    const int rdbase = hi * 128 + col * 16;

    // zero H buffer 0 (4 KB = 1024 dwords)
    for (int t = tid; t < 1024; t += 512) ((unsigned int*)lds)[t] = 0u;

    f32x4 hs = (f32x4)0.0f;  // running sum for this lane's tile (sel)

    // gate group 0 (steps 0..63) before first xw reads
    wait_group(gcnt, 0);

    // per-lane xw base: xw[s][bbase+col][rowbase + mt*16 + hi*4 + r]
    const float* xwl = xw + (size_t)(bbase + col) * H_ + rowbase + hi * 4;
    // 4-slot rotation of xw-as-C-operand buffers (distance-2 prefetch)
    f32x4 cv[4][2];
    cv[0][0] = *(const f32x4*)(xwl);                  // s = 0
    cv[0][1] = *(const f32x4*)(xwl + 16);
    cv[1][0] = *(const f32x4*)(xwl + 16384);          // s = 1
    cv[1][1] = *(const f32x4*)(xwl + 16384 + 16);
    __syncthreads();  // zero-init visible

#define STEP(CUR, I, SBASE)                                                    \
    {                                                                          \
        int sp = (SBASE) + 2;                                                  \
        if (sp < S_ && (sp & 63) == 0) wait_group(gcnt, sp >> 6);              \
        if (sp > S_ - 1) sp = S_ - 1;                                          \
        cv[(I + 2) & 3][0] = *(const f32x4*)(xwl + (size_t)sp * 16384);        \
        cv[(I + 2) & 3][1] = *(const f32x4*)(xwl + (size_t)sp * 16384 + 16);   \
        h8_t bf[8];                                                            \
        _Pragma("unroll") for (int ks = 0; ks < 8; ++ks)                       \
            bf[ks] = *(const h8_t*)(lds + (CUR)*4096 + rdbase + ks * 512);     \
        _Pragma("unroll") for (int ks = 0; ks < 8; ++ks) {                     \
            cv[I][0] = __builtin_amdgcn_mfma_f32_16x16x32_f16(                 \
                a[0][ks], bf[ks], cv[I][0], 0, 0, 0);                          \
            cv[I][1] = __builtin_amdgcn_mfma_f32_16x16x32_f16(                 \
                a[1][ks], bf[ks], cv[I][1], 0, 0, 0);                          \
        }                                                                      \
        {                                                                      \
            f32x4 sv = (sel == 0) ? cv[I][0] : cv[I][1];                       \
            float h0 = fast_tanh(sv[0]);                                       \
            float h1 = fast_tanh(sv[1]);                                       \
            float h2 = fast_tanh(sv[2]);                                       \
            float h3 = fast_tanh(sv[3]);                                       \
            hs[0] += h0; hs[1] += h1; hs[2] += h2; hs[3] += h3;                \
            uint2 pk;                                                          \
            pk.x = __builtin_bit_cast(unsigned int,                            \
                                      __builtin_amdgcn_cvt_pkrtz(h0, h1));     \
            pk.y = __builtin_bit_cast(unsigned int,                            \
                                      __builtin_amdgcn_cvt_pkrtz(h2, h3));     \
            *(uint2*)(lds + ((CUR) ^ 1) * 4096 + wboff) = pk;                  \
        }                                                                      \
        asm volatile("s_waitcnt lgkmcnt(0)" ::: "memory");                     \
        __builtin_amdgcn_s_barrier();                                          \
    }

    for (int s = 0; s < S_; s += 4) {
        STEP(0, 0, s)
        STEP(1, 1, s + 1)
        STEP(0, 2, s + 2)
        STEP(1, 3, s + 3)
    }
#undef STEP

    // ---- fused output epilogue: logits + log_softmax for cols bbase..+7 ----
    // Stage hs into the (dead) H-buffer as f32 [col][k]: 8 cols x 256 k = 8KB.
    {
        const int k0v = rowbase + sel * 16 + hi * 4;
        *(f32x4*)(lds + col * 1024 + k0v * 4) = hs;
    }
    __syncthreads();
    // wave w handles batch element b = bbase + w
    {
        const float* hrow = (const float*)(lds + w * 1024);
        float lg[C_];
#pragma unroll
        for (int c = 0; c < C_; ++c) {
            float p = 0.0f;
#pragma unroll
            for (int q = 0; q < 4; ++q)
                p = fmaf(hrow[l + 64 * q], W_out[c * H_ + l + 64 * q], p);
#pragma unroll
            for (int off = 32; off; off >>= 1) p += __shfl_xor(p, off);
            lg[c] = p + (float)S_ * b_out[c];
        }
        if (l == 0) {
            float m = lg[0];
#pragma unroll
            for (int c = 1; c < C_; ++c) m = fmaxf(m, lg[c]);
            float sum = 0.0f;
#pragma unroll
            for (int c = 0; c < C_; ++c) sum += expf(lg[c] - m);
            float lse = logf(sum);
#pragma unroll
            for (int c = 0; c < C_; ++c)
                out[(bbase + w) * C_ + c] = lg[c] - m - lse;
        }
    }
}

// ---------------------------------------------------------------------------
extern "C" void kernel_launch(void* const* d_in, const int* in_sizes, int n_in,
                              void* d_out, int out_size, void* d_ws,
                              size_t ws_size, hipStream_t stream) {
    const int* idx = (const int*)d_in[0];
    const float* emb = (const float*)d_in[1];
    const float* W_ih = (const float*)d_in[2];
    const float* W_hh = (const float*)d_in[3];
    const float* b_ih = (const float*)d_in[4];
    const float* b_hh = (const float*)d_in[5];
    const float* W_out = (const float*)d_in[6];
    const float* b_out = (const float*)d_in[7];
    float* out = (float*)d_out;

    float* ws = (float*)d_ws;
    float* xw = ws;                               // S*B*H floats
    unsigned* gcnt = (unsigned*)(xw + (size_t)S_ * B_ * H_);  // 8 u32

    hipMemsetAsync(gcnt, 0, 8 * sizeof(unsigned), stream);
    hipLaunchKernelGGL(fused_kernel, dim3(8 + NPROD), dim3(512), 0, stream,
                       idx, emb, W_ih, b_ih, b_hh, xw, W_hh, W_out, b_out, out,
                       gcnt);
}

// Round 18
// 272.431 us; speedup vs baseline: 1.1053x; 1.0403x over previous
//
#include <hip/hip_runtime.h>
#include <stdint.h>

#define S_ 512
#define B_ 64
#define V_ 50000
#define E_ 300
#define H_ 256
#define C_ 5

typedef _Float16 h8_t __attribute__((ext_vector_type(8)));
typedef float f32x4 __attribute__((ext_vector_type(4)));

// tanh(x) = 1 - 2/(e^{2x}+1); e^{2x}=2^{2x*log2e}.
__device__ __forceinline__ float fast_tanh(float x) {
    float e = __builtin_amdgcn_exp2f(x * 2.88539008177793f);  // 2*log2(e)
    return fmaf(-2.0f, __builtin_amdgcn_rcpf(e + 1.0f), 1.0f);
}

// B-fragment of W_ih for the xw GEMM, loaded directly from f32 (no prep
// kernel — R17-validated): lane (n,hi), h = row, e0 = ks*32 + hi*8.
__device__ __forceinline__ h8_t load_wfrag(const float* __restrict__ W,
                                           int h, int e0) {
    h8_t v;
    if (e0 + 8 <= E_) {
        float4 f0 = *(const float4*)(W + (size_t)h * E_ + e0);
        float4 f1 = *(const float4*)(W + (size_t)h * E_ + e0 + 4);
        v[0] = (_Float16)f0.x; v[1] = (_Float16)f0.y;
        v[2] = (_Float16)f0.z; v[3] = (_Float16)f0.w;
        v[4] = (_Float16)f1.x; v[5] = (_Float16)f1.y;
        v[6] = (_Float16)f1.z; v[7] = (_Float16)f1.w;
    } else if (e0 < E_) {  // e0 = 296: last 4 real + 4 pad
        float4 f0 = *(const float4*)(W + (size_t)h * E_ + e0);
        v[0] = (_Float16)f0.x; v[1] = (_Float16)f0.y;
        v[2] = (_Float16)f0.z; v[3] = (_Float16)f0.w;
        v[4] = (_Float16)0.0f; v[5] = (_Float16)0.0f;
        v[6] = (_Float16)0.0f; v[7] = (_Float16)0.0f;
    } else {
        v = (h8_t)(_Float16)0.0f;
    }
    return v;
}

// ---------------------------------------------------------------------------
// Kernel B: xw[s,b,h] = sum_e emb[idx[s,b],e]*W_ih[h,e] + b_ih[h] + b_hh[h]
// MFMA, 512 blocks x 512 threads (8 waves). W_ih fragments loaded DIRECTLY
// from f32 (wb_prep kernel dropped; branches in load_wfrag fold at compile
// time since ks is unrolled). R7/R17-validated structure, ~27us.
// ---------------------------------------------------------------------------
__global__ __launch_bounds__(512, 2) void xw_kernel(
    const int* __restrict__ idx, const float* __restrict__ emb,
    const float* __restrict__ W_ih, const float* __restrict__ b_ih,
    const float* __restrict__ b_hh, float* __restrict__ xw) {
    __shared__ uint4 Afrag[4 * 10 * 64];  // 40 KB
    const int tid = threadIdx.x;
    const int w = tid >> 6;  // wave 0..7
    const int l = tid & 63;
    const int n = l & 15;
    const int hi = l >> 4;
    const int base = blockIdx.x * 64;

    // W_ih B-fragments for this wave's 32 cols: 80 regs, loop-invariant
    h8_t bw0[10], bw1[10];
#pragma unroll
    for (int ks = 0; ks < 10; ++ks) {
        bw0[ks] = load_wfrag(W_ih, (2 * w) * 16 + n, ks * 32 + hi * 8);
        bw1[ks] = load_wfrag(W_ih, (2 * w + 1) * 16 + n, ks * 32 + hi * 8);
    }
    const float bias0 = b_ih[w * 32 + n] + b_hh[w * 32 + n];
    const float bias1 = b_ih[w * 32 + 16 + n] + b_hh[w * 32 + 16 + n];

    for (int cc = tid; cc < 64 * 40; cc += 512) {
        int m = cc / 40;
        int c = cc - m * 40;  // chunk: e = 8c..8c+7
        int ks = c >> 2;
        int hic = c & 3;
        const float* src = emb + (size_t)idx[base + m] * E_ + 8 * c;
        h8_t v;
        if (c < 37) {
            float4 f0 = *(const float4*)src;
            float4 f1 = *(const float4*)(src + 4);
            v[0] = (_Float16)f0.x; v[1] = (_Float16)f0.y;
            v[2] = (_Float16)f0.z; v[3] = (_Float16)f0.w;
            v[4] = (_Float16)f1.x; v[5] = (_Float16)f1.y;
            v[6] = (_Float16)f1.z; v[7] = (_Float16)f1.w;
        } else if (c == 37) {
            float4 f0 = *(const float4*)src;
            v[0] = (_Float16)f0.x; v[1] = (_Float16)f0.y;
            v[2] = (_Float16)f0.z; v[3] = (_Float16)f0.w;
            v[4] = (_Float16)0.0f; v[5] = (_Float16)0.0f;
            v[6] = (_Float16)0.0f; v[7] = (_Float16)0.0f;
        } else {
            v = (h8_t)(_Float16)0.0f;
        }
        int fl = (hic << 4) | (m & 15);
        int mt = m >> 4;
        Afrag[(mt * 10 + ks) * 64 + fl] = __builtin_bit_cast(uint4, v);
    }
    __syncthreads();

    f32x4 c[4][2];
#pragma unroll
    for (int mt = 0; mt < 4; ++mt) {
        c[mt][0] = (f32x4)bias0;
        c[mt][1] = (f32x4)bias1;
    }
#pragma unroll
    for (int ks = 0; ks < 10; ++ks) {
#pragma unroll
        for (int mt = 0; mt < 4; ++mt) {
            h8_t a = __builtin_bit_cast(h8_t, Afrag[(mt * 10 + ks) * 64 + l]);
            c[mt][0] = __builtin_amdgcn_mfma_f32_16x16x32_f16(a, bw0[ks],
                                                              c[mt][0], 0, 0, 0);
            c[mt][1] = __builtin_amdgcn_mfma_f32_16x16x32_f16(a, bw1[ks],
                                                              c[mt][1], 0, 0, 0);
        }
    }
#pragma unroll
    for (int mt = 0; mt < 4; ++mt)
#pragma unroll
        for (int q = 0; q < 2; ++q) {
            float* op =
                xw + (size_t)(base + mt * 16 + hi * 4) * H_ + w * 32 + q * 16 + n;
#pragma unroll
            for (int r = 0; r < 4; ++r) op[(size_t)r * H_] = c[mt][q][r];
        }
}

// ---------------------------------------------------------------------------
// Kernel C: MFMA recurrence, BROADCAST-8 + SPLIT EPILOGUE (R14, 231us) +
// DEPTH-4 CHAIN SPLIT + FUSED OUTPUT EPILOGUE.
// 8 blocks x 8 batch cols, 512 threads (8 waves, 2 waves/SIMD).
//
// Chain split (new): R14's 8-deep dependent MFMA accumulation exposed
// ~200cyc/step at 2 waves/SIMD (MfmaUtil(active) 45% vs 57% pipe demand).
// Each tile now accumulates as TWO depth-4 chains: ks0..3 seeded with
// xw-as-C, ks4..7 seeded with zero. Only the lane's SELECTED tile needs the
// combine (the other tile's sum is consumed by the paired lane n^8):
// 2 selects + 4 adds. 4 independent chains x depth 4.
//
// Fused out epilogue (R17-validated): hsum staged in the dead H-buffer LDS,
// wave w computes batch col bbase+w's 5 logits + log_softmax, lane 0 writes.
//
//   Per-buffer LDS layout (4KB), col c in 0..7, k in 0..255:
//     byte(k, c) = (k>>3)*128 + c*16 + (k&7)*2
//   read:  lane l (n=l&15, hi=l>>4, col=n&7), slice ks ->
//          b128 at ks*512 + hi*128 + col*16     [n, n+8 same addr: free]
//   write: lane (w,hi,n), tile sel=n>>3: rows k0..k0+3, col,
//          b64 at (w*4 + sel*2 + (hi>>1))*128 + col*16 + (hi&1)*8
//   Light barrier (lgkmcnt only) + distance-2 xw prefetch, 4-slot rotation.
// ---------------------------------------------------------------------------
__global__ __launch_bounds__(512, 2) void rnn_kernel(
    const float* __restrict__ xw, const float* __restrict__ W_hh,
    const float* __restrict__ W_out, const float* __restrict__ b_out,
    float* __restrict__ out) {
    const int tid = threadIdx.x;
    const int w = tid >> 6;  // wave 0..7, rows 32w..32w+31
    const int l = tid & 63;
    const int n = l & 15;    // A row / B col / C col (0..15)
    const int hi = l >> 4;   // k-group
    const int col = n & 7;   // real batch col within block
    const int sel = n >> 3;  // epilogue tile handled by this lane (0 or 1)
    const int bbase = blockIdx.x * 8;
    const int rowbase = w * 32;

    __shared__ __attribute__((aligned(16))) unsigned char smem[8192];
    char* lds = (char*)smem;  // [2][4096] H double-buffer

    // ---- A fragments: W_hh rows rowbase..rowbase+31 as f16 (64 regs) ----
    h8_t a[2][8];
#pragma unroll
    for (int mt = 0; mt < 2; ++mt) {
        const float* wr = W_hh + (size_t)(rowbase + mt * 16 + n) * H_;
#pragma unroll
        for (int ks = 0; ks < 8; ++ks) {
            const float* wp = wr + ks * 32 + hi * 8;
            float4 f0 = *(const float4*)wp;
            float4 f1 = *(const float4*)(wp + 4);
            h8_t v;
            v[0] = (_Float16)f0.x; v[1] = (_Float16)f0.y;
            v[2] = (_Float16)f0.z; v[3] = (_Float16)f0.w;
            v[4] = (_Float16)f1.x; v[5] = (_Float16)f1.y;
            v[6] = (_Float16)f1.z; v[7] = (_Float16)f1.w;
            a[mt][ks] = v;
        }
    }

    // H'-write byte offset (buffer-relative): tile sel, rows k0..k0+3, col
    const int wboff =
        (w * 4 + sel * 2 + (hi >> 1)) * 128 + col * 16 + (hi & 1) * 8;
    // B-read base (buffer-relative); full addr: CUR*4096 + rdbase + ks*512
    const int rdbase = hi * 128 + col * 16;

    // zero H buffer 0 (4 KB = 1024 dwords)
    for (int t = tid; t < 1024; t += 512) ((unsigned int*)lds)[t] = 0u;

    f32x4 hs = (f32x4)0.0f;  // running sum for this lane's tile (sel)

    // per-lane xw base: xw[s][bbase+col][rowbase + mt*16 + hi*4 + r]
    const float* xwl = xw + (size_t)(bbase + col) * H_ + rowbase + hi * 4;
    // 4-slot rotation of xw-as-C-operand buffers (distance-2 prefetch)
    f32x4 cv[4][2];
    cv[0][0] = *(const f32x4*)(xwl);                  // s = 0
    cv[0][1] = *(const f32x4*)(xwl + 16);
    cv[1][0] = *(const f32x4*)(xwl + 16384);          // s = 1
    cv[1][1] = *(const f32x4*)(xwl + 16384 + 16);
    __syncthreads();  // zero-init visible

#define STEP(CUR, I, SBASE)                                                    \
    {                                                                          \
        int sp = (SBASE) + 2;                                                  \
        if (sp > S_ - 1) sp = S_ - 1;                                          \
        cv[(I + 2) & 3][0] = *(const f32x4*)(xwl + (size_t)sp * 16384);        \
        cv[(I + 2) & 3][1] = *(const f32x4*)(xwl + (size_t)sp * 16384 + 16);   \
        h8_t bf[8];                                                            \
        _Pragma("unroll") for (int ks = 0; ks < 8; ++ks)                       \
            bf[ks] = *(const h8_t*)(lds + (CUR)*4096 + rdbase + ks * 512);     \
        f32x4 c0a = cv[I][0], c1a = cv[I][1];                                  \
        f32x4 c0b = (f32x4)0.0f, c1b = (f32x4)0.0f;                            \
        _Pragma("unroll") for (int ks = 0; ks < 4; ++ks) {                     \
            c0a = __builtin_amdgcn_mfma_f32_16x16x32_f16(a[0][ks], bf[ks],     \
                                                         c0a, 0, 0, 0);        \
            c1a = __builtin_amdgcn_mfma_f32_16x16x32_f16(a[1][ks], bf[ks],     \
                                                         c1a, 0, 0, 0);        \
            c0b = __builtin_amdgcn_mfma_f32_16x16x32_f16(                      \
                a[0][ks + 4], bf[ks + 4], c0b, 0, 0, 0);                       \
            c1b = __builtin_amdgcn_mfma_f32_16x16x32_f16(                      \
                a[1][ks + 4], bf[ks + 4], c1b, 0, 0, 0);                       \
        }                                                                      \
        {                                                                      \
            f32x4 sva = (sel == 0) ? c0a : c1a;                                \
            f32x4 svb = (sel == 0) ? c0b : c1b;                                \
            f32x4 sv = sva + svb;                                              \
            float h0 = fast_tanh(sv[0]);                                       \
            float h1 = fast_tanh(sv[1]);                                       \
            float h2 = fast_tanh(sv[2]);                                       \
            float h3 = fast_tanh(sv[3]);                                       \
            hs[0] += h0; hs[1] += h1; hs[2] += h2; hs[3] += h3;                \
            uint2 pk;                                                          \
            pk.x = __builtin_bit_cast(unsigned int,                            \
                                      __builtin_amdgcn_cvt_pkrtz(h0, h1));     \
            pk.y = __builtin_bit_cast(unsigned int,                            \
                                      __builtin_amdgcn_cvt_pkrtz(h2, h3));     \
            *(uint2*)(lds + ((CUR) ^ 1) * 4096 + wboff) = pk;                  \
        }                                                                      \
        asm volatile("s_waitcnt lgkmcnt(0)" ::: "memory");                     \
        __builtin_amdgcn_s_barrier();                                          \
    }

    for (int s = 0; s < S_; s += 4) {
        STEP(0, 0, s)
        STEP(1, 1, s + 1)
        STEP(0, 2, s + 2)
        STEP(1, 3, s + 3)
    }
#undef STEP

    // ---- fused output epilogue: logits + log_softmax for cols bbase..+7 ----
    // Stage hs into the (dead) H-buffer as f32 [col][k]: 8 cols x 256 = 8KB.
    {
        const int k0v = rowbase + sel * 16 + hi * 4;
        *(f32x4*)(lds + col * 1024 + k0v * 4) = hs;
    }
    __syncthreads();
    // wave w handles batch element b = bbase + w
    {
        const float* hrow = (const float*)(lds + w * 1024);
        float lg[C_];
#pragma unroll
        for (int c = 0; c < C_; ++c) {
            float p = 0.0f;
#pragma unroll
            for (int q = 0; q < 4; ++q)
                p = fmaf(hrow[l + 64 * q], W_out[c * H_ + l + 64 * q], p);
#pragma unroll
            for (int off = 32; off; off >>= 1) p += __shfl_xor(p, off);
            lg[c] = p + (float)S_ * b_out[c];
        }
        if (l == 0) {
            float m = lg[0];
#pragma unroll
            for (int c = 1; c < C_; ++c) m = fmaxf(m, lg[c]);
            float sum = 0.0f;
#pragma unroll
            for (int c = 0; c < C_; ++c) sum += expf(lg[c] - m);
            float lse = logf(sum);
#pragma unroll
            for (int c = 0; c < C_; ++c)
                out[(bbase + w) * C_ + c] = lg[c] - m - lse;
        }
    }
}

// ---------------------------------------------------------------------------
extern "C" void kernel_launch(void* const* d_in, const int* in_sizes, int n_in,
                              void* d_out, int out_size, void* d_ws,
                              size_t ws_size, hipStream_t stream) {
    const int* idx = (const int*)d_in[0];
    const float* emb = (const float*)d_in[1];
    const float* W_ih = (const float*)d_in[2];
    const float* W_hh = (const float*)d_in[3];
    const float* b_ih = (const float*)d_in[4];
    const float* b_hh = (const float*)d_in[5];
    const float* W_out = (const float*)d_in[6];
    const float* b_out = (const float*)d_in[7];
    float* out = (float*)d_out;

    float* xw = (float*)d_ws;  // S*B*H floats

    hipLaunchKernelGGL(xw_kernel, dim3((S_ * B_) / 64), dim3(512), 0, stream,
                       idx, emb, W_ih, b_ih, b_hh, xw);
    hipLaunchKernelGGL(rnn_kernel, dim3(8), dim3(512), 0, stream, xw, W_hh,
                       W_out, b_out, out);
}

// Round 19
// 265.994 us; speedup vs baseline: 1.1321x; 1.0242x over previous
//
#include <hip/hip_runtime.h>
#include <stdint.h>

#define S_ 512
#define B_ 64
#define V_ 50000
#define E_ 300
#define H_ 256
#define C_ 5

typedef _Float16 h8_t __attribute__((ext_vector_type(8)));
typedef float f32x4 __attribute__((ext_vector_type(4)));

// tanh(x) = 1 - 2/(e^{2x}+1); e^{2x}=2^{2x*log2e}.
__device__ __forceinline__ float fast_tanh(float x) {
    float e = __builtin_amdgcn_exp2f(x * 2.88539008177793f);  // 2*log2(e)
    return fmaf(-2.0f, __builtin_amdgcn_rcpf(e + 1.0f), 1.0f);
}

// B-fragment of W_ih for the xw GEMM, loaded directly from f32 (no prep
// kernel — R17-validated): lane (n,hi), h = row, e0 = ks*32 + hi*8.
__device__ __forceinline__ h8_t load_wfrag(const float* __restrict__ W,
                                           int h, int e0) {
    h8_t v;
    if (e0 + 8 <= E_) {
        float4 f0 = *(const float4*)(W + (size_t)h * E_ + e0);
        float4 f1 = *(const float4*)(W + (size_t)h * E_ + e0 + 4);
        v[0] = (_Float16)f0.x; v[1] = (_Float16)f0.y;
        v[2] = (_Float16)f0.z; v[3] = (_Float16)f0.w;
        v[4] = (_Float16)f1.x; v[5] = (_Float16)f1.y;
        v[6] = (_Float16)f1.z; v[7] = (_Float16)f1.w;
    } else if (e0 < E_) {  // e0 = 296: last 4 real + 4 pad
        float4 f0 = *(const float4*)(W + (size_t)h * E_ + e0);
        v[0] = (_Float16)f0.x; v[1] = (_Float16)f0.y;
        v[2] = (_Float16)f0.z; v[3] = (_Float16)f0.w;
        v[4] = (_Float16)0.0f; v[5] = (_Float16)0.0f;
        v[6] = (_Float16)0.0f; v[7] = (_Float16)0.0f;
    } else {
        v = (h8_t)(_Float16)0.0f;
    }
    return v;
}

// ---------------------------------------------------------------------------
// Kernel B: xw[s,b,h] = sum_e emb[idx[s,b],e]*W_ih[h,e] + b_ih[h] + b_hh[h]
// MFMA, 512 blocks x 512 threads (8 waves). W_ih fragments loaded DIRECTLY
// from f32. R7/R17/R18-validated structure, ~27us.
// ---------------------------------------------------------------------------
__global__ __launch_bounds__(512, 2) void xw_kernel(
    const int* __restrict__ idx, const float* __restrict__ emb,
    const float* __restrict__ W_ih, const float* __restrict__ b_ih,
    const float* __restrict__ b_hh, float* __restrict__ xw) {
    __shared__ uint4 Afrag[4 * 10 * 64];  // 40 KB
    const int tid = threadIdx.x;
    const int w = tid >> 6;  // wave 0..7
    const int l = tid & 63;
    const int n = l & 15;
    const int hi = l >> 4;
    const int base = blockIdx.x * 64;

    // W_ih B-fragments for this wave's 32 cols: 80 regs, loop-invariant
    h8_t bw0[10], bw1[10];
#pragma unroll
    for (int ks = 0; ks < 10; ++ks) {
        bw0[ks] = load_wfrag(W_ih, (2 * w) * 16 + n, ks * 32 + hi * 8);
        bw1[ks] = load_wfrag(W_ih, (2 * w + 1) * 16 + n, ks * 32 + hi * 8);
    }
    const float bias0 = b_ih[w * 32 + n] + b_hh[w * 32 + n];
    const float bias1 = b_ih[w * 32 + 16 + n] + b_hh[w * 32 + 16 + n];

    for (int cc = tid; cc < 64 * 40; cc += 512) {
        int m = cc / 40;
        int c = cc - m * 40;  // chunk: e = 8c..8c+7
        int ks = c >> 2;
        int hic = c & 3;
        const float* src = emb + (size_t)idx[base + m] * E_ + 8 * c;
        h8_t v;
        if (c < 37) {
            float4 f0 = *(const float4*)src;
            float4 f1 = *(const float4*)(src + 4);
            v[0] = (_Float16)f0.x; v[1] = (_Float16)f0.y;
            v[2] = (_Float16)f0.z; v[3] = (_Float16)f0.w;
            v[4] = (_Float16)f1.x; v[5] = (_Float16)f1.y;
            v[6] = (_Float16)f1.z; v[7] = (_Float16)f1.w;
        } else if (c == 37) {
            float4 f0 = *(const float4*)src;
            v[0] = (_Float16)f0.x; v[1] = (_Float16)f0.y;
            v[2] = (_Float16)f0.z; v[3] = (_Float16)f0.w;
            v[4] = (_Float16)0.0f; v[5] = (_Float16)0.0f;
            v[6] = (_Float16)0.0f; v[7] = (_Float16)0.0f;
        } else {
            v = (h8_t)(_Float16)0.0f;
        }
        int fl = (hic << 4) | (m & 15);
        int mt = m >> 4;
        Afrag[(mt * 10 + ks) * 64 + fl] = __builtin_bit_cast(uint4, v);
    }
    __syncthreads();

    f32x4 c[4][2];
#pragma unroll
    for (int mt = 0; mt < 4; ++mt) {
        c[mt][0] = (f32x4)bias0;
        c[mt][1] = (f32x4)bias1;
    }
#pragma unroll
    for (int ks = 0; ks < 10; ++ks) {
#pragma unroll
        for (int mt = 0; mt < 4; ++mt) {
            h8_t a = __builtin_bit_cast(h8_t, Afrag[(mt * 10 + ks) * 64 + l]);
            c[mt][0] = __builtin_amdgcn_mfma_f32_16x16x32_f16(a, bw0[ks],
                                                              c[mt][0], 0, 0, 0);
            c[mt][1] = __builtin_amdgcn_mfma_f32_16x16x32_f16(a, bw1[ks],
                                                              c[mt][1], 0, 0, 0);
        }
    }
#pragma unroll
    for (int mt = 0; mt < 4; ++mt)
#pragma unroll
        for (int q = 0; q < 2; ++q) {
            float* op =
                xw + (size_t)(base + mt * 16 + hi * 4) * H_ + w * 32 + q * 16 + n;
#pragma unroll
            for (int r = 0; r < 4; ++r) op[(size_t)r * H_] = c[mt][q][r];
        }
}

// ---------------------------------------------------------------------------
// Kernel C: MFMA recurrence, BROADCAST-8 + SPLIT EPILOGUE (R14's proven
// 8-deep xw-as-C accumulation — R18's depth-4 chain split REVERTED: it cost
// +6us in extra VALU/reseed) + FUSED OUTPUT EPILOGUE (R17/R18-validated).
// 8 blocks x 8 batch cols, 512 threads (8 waves, 2 waves/SIMD).
//
//   Per-buffer LDS layout (4KB), col c in 0..7, k in 0..255:
//     byte(k, c) = (k>>3)*128 + c*16 + (k&7)*2
//   read:  lane l (n=l&15, hi=l>>4, col=n&7), slice ks ->
//          b128 at ks*512 + hi*128 + col*16     [n, n+8 same addr: free]
//   write: lane (w,hi,n), tile sel=n>>3: rows k0..k0+3, col,
//          b64 at (w*4 + sel*2 + (hi>>1))*128 + col*16 + (hi&1)*8
//   Light barrier (lgkmcnt only) + distance-2 xw prefetch, 4-slot rotation.
//   Epilogue: lane handles tile sel only (pair lane n^8 covers the other):
//   4 tanh, 2 cvt_pk, 1 b64 H'-write, f32x4 hsum in regs.
//   Final: hsum staged to dead H-buffer LDS; wave w computes batch col
//   bbase+w's 5 logits (shfl_xor reduce) + log_softmax; lane 0 writes out.
// ---------------------------------------------------------------------------
__global__ __launch_bounds__(512, 2) void rnn_kernel(
    const float* __restrict__ xw, const float* __restrict__ W_hh,
    const float* __restrict__ W_out, const float* __restrict__ b_out,
    float* __restrict__ out) {
    const int tid = threadIdx.x;
    const int w = tid >> 6;  // wave 0..7, rows 32w..32w+31
    const int l = tid & 63;
    const int n = l & 15;    // A row / B col / C col (0..15)
    const int hi = l >> 4;   // k-group
    const int col = n & 7;   // real batch col within block
    const int sel = n >> 3;  // epilogue tile handled by this lane (0 or 1)
    const int bbase = blockIdx.x * 8;
    const int rowbase = w * 32;

    __shared__ __attribute__((aligned(16))) unsigned char smem[8192];
    char* lds = (char*)smem;  // [2][4096] H double-buffer

    // ---- A fragments: W_hh rows rowbase..rowbase+31 as f16 (64 regs) ----
    h8_t a[2][8];
#pragma unroll
    for (int mt = 0; mt < 2; ++mt) {
        const float* wr = W_hh + (size_t)(rowbase + mt * 16 + n) * H_;
#pragma unroll
        for (int ks = 0; ks < 8; ++ks) {
            const float* wp = wr + ks * 32 + hi * 8;
            float4 f0 = *(const float4*)wp;
            float4 f1 = *(const float4*)(wp + 4);
            h8_t v;
            v[0] = (_Float16)f0.x; v[1] = (_Float16)f0.y;
            v[2] = (_Float16)f0.z; v[3] = (_Float16)f0.w;
            v[4] = (_Float16)f1.x; v[5] = (_Float16)f1.y;
            v[6] = (_Float16)f1.z; v[7] = (_Float16)f1.w;
            a[mt][ks] = v;
        }
    }

    // H'-write byte offset (buffer-relative): tile sel, rows k0..k0+3, col
    const int wboff =
        (w * 4 + sel * 2 + (hi >> 1)) * 128 + col * 16 + (hi & 1) * 8;
    // B-read base (buffer-relative); full addr: CUR*4096 + rdbase + ks*512
    const int rdbase = hi * 128 + col * 16;

    // zero H buffer 0 (4 KB = 1024 dwords)
    for (int t = tid; t < 1024; t += 512) ((unsigned int*)lds)[t] = 0u;

    f32x4 hs = (f32x4)0.0f;  // running sum for this lane's tile (sel)

    // per-lane xw base: xw[s][bbase+col][rowbase + mt*16 + hi*4 + r]
    const float* xwl = xw + (size_t)(bbase + col) * H_ + rowbase + hi * 4;
    // 4-slot rotation of xw-as-C-operand buffers (distance-2 prefetch)
    f32x4 cv[4][2];
    cv[0][0] = *(const f32x4*)(xwl);                  // s = 0
    cv[0][1] = *(const f32x4*)(xwl + 16);
    cv[1][0] = *(const f32x4*)(xwl + 16384);          // s = 1
    cv[1][1] = *(const f32x4*)(xwl + 16384 + 16);
    __syncthreads();  // zero-init visible

#define STEP(CUR, I, SBASE)                                                    \
    {                                                                          \
        int sp = (SBASE) + 2;                                                  \
        if (sp > S_ - 1) sp = S_ - 1;                                          \
        cv[(I + 2) & 3][0] = *(const f32x4*)(xwl + (size_t)sp * 16384);        \
        cv[(I + 2) & 3][1] = *(const f32x4*)(xwl + (size_t)sp * 16384 + 16);   \
        h8_t bf[8];                                                            \
        _Pragma("unroll") for (int ks = 0; ks < 8; ++ks)                       \
            bf[ks] = *(const h8_t*)(lds + (CUR)*4096 + rdbase + ks * 512);     \
        _Pragma("unroll") for (int ks = 0; ks < 8; ++ks) {                     \
            cv[I][0] = __builtin_amdgcn_mfma_f32_16x16x32_f16(                 \
                a[0][ks], bf[ks], cv[I][0], 0, 0, 0);                          \
            cv[I][1] = __builtin_amdgcn_mfma_f32_16x16x32_f16(                 \
                a[1][ks], bf[ks], cv[I][1], 0, 0, 0);                          \
        }                                                                      \
        {                                                                      \
            f32x4 sv = (sel == 0) ? cv[I][0] : cv[I][1];                       \
            float h0 = fast_tanh(sv[0]);                                       \
            float h1 = fast_tanh(sv[1]);                                       \
            float h2 = fast_tanh(sv[2]);                                       \
            float h3 = fast_tanh(sv[3]);                                       \
            hs[0] += h0; hs[1] += h1; hs[2] += h2; hs[3] += h3;                \
            uint2 pk;                                                          \
            pk.x = __builtin_bit_cast(unsigned int,                            \
                                      __builtin_amdgcn_cvt_pkrtz(h0, h1));     \
            pk.y = __builtin_bit_cast(unsigned int,                            \
                                      __builtin_amdgcn_cvt_pkrtz(h2, h3));     \
            *(uint2*)(lds + ((CUR) ^ 1) * 4096 + wboff) = pk;                  \
        }                                                                      \
        asm volatile("s_waitcnt lgkmcnt(0)" ::: "memory");                     \
        __builtin_amdgcn_s_barrier();                                          \
    }

    for (int s = 0; s < S_; s += 4) {
        STEP(0, 0, s)
        STEP(1, 1, s + 1)
        STEP(0, 2, s + 2)
        STEP(1, 3, s + 3)
    }
#undef STEP

    // ---- fused output epilogue: logits + log_softmax for cols bbase..+7 ----
    // Stage hs into the (dead) H-buffer as f32 [col][k]: 8 cols x 256 = 8KB.
    {
        const int k0v = rowbase + sel * 16 + hi * 4;
        *(f32x4*)(lds + col * 1024 + k0v * 4) = hs;
    }
    __syncthreads();
    // wave w handles batch element b = bbase + w
    {
        const float* hrow = (const float*)(lds + w * 1024);
        float lg[C_];
#pragma unroll
        for (int c = 0; c < C_; ++c) {
            float p = 0.0f;
#pragma unroll
            for (int q = 0; q < 4; ++q)
                p = fmaf(hrow[l + 64 * q], W_out[c * H_ + l + 64 * q], p);
#pragma unroll
            for (int off = 32; off; off >>= 1) p += __shfl_xor(p, off);
            lg[c] = p + (float)S_ * b_out[c];
        }
        if (l == 0) {
            float m = lg[0];
#pragma unroll
            for (int c = 1; c < C_; ++c) m = fmaxf(m, lg[c]);
            float sum = 0.0f;
#pragma unroll
            for (int c = 0; c < C_; ++c) sum += expf(lg[c] - m);
            float lse = logf(sum);
#pragma unroll
            for (int c = 0; c < C_; ++c)
                out[(bbase + w) * C_ + c] = lg[c] - m - lse;
        }
    }
}

// ---------------------------------------------------------------------------
extern "C" void kernel_launch(void* const* d_in, const int* in_sizes, int n_in,
                              void* d_out, int out_size, void* d_ws,
                              size_t ws_size, hipStream_t stream) {
    const int* idx = (const int*)d_in[0];
    const float* emb = (const float*)d_in[1];
    const float* W_ih = (const float*)d_in[2];
    const float* W_hh = (const float*)d_in[3];
    const float* b_ih = (const float*)d_in[4];
    const float* b_hh = (const float*)d_in[5];
    const float* W_out = (const float*)d_in[6];
    const float* b_out = (const float*)d_in[7];
    float* out = (float*)d_out;

    float* xw = (float*)d_ws;  // S*B*H floats

    hipLaunchKernelGGL(xw_kernel, dim3((S_ * B_) / 64), dim3(512), 0, stream,
                       idx, emb, W_ih, b_ih, b_hh, xw);
    hipLaunchKernelGGL(rnn_kernel, dim3(8), dim3(512), 0, stream, xw, W_hh,
                       W_out, b_out, out);
}

// Round 20
// 265.736 us; speedup vs baseline: 1.1332x; 1.0010x over previous
//
#include <hip/hip_runtime.h>
#include <stdint.h>

#define S_ 512
#define B_ 64
#define V_ 50000
#define E_ 300
#define H_ 256
#define C_ 5

typedef _Float16 h8_t __attribute__((ext_vector_type(8)));
typedef float f32x4 __attribute__((ext_vector_type(4)));

// tanh(x) = 1 - 2/(e^{2x}+1); e^{2x}=2^{2x*log2e}.
__device__ __forceinline__ float fast_tanh(float x) {
    float e = __builtin_amdgcn_exp2f(x * 2.88539008177793f);  // 2*log2(e)
    return fmaf(-2.0f, __builtin_amdgcn_rcpf(e + 1.0f), 1.0f);
}

// B-fragment of W_ih for the xw GEMM, loaded directly from f32.
__device__ __forceinline__ h8_t load_wfrag(const float* __restrict__ W,
                                           int h, int e0) {
    h8_t v;
    if (e0 + 8 <= E_) {
        float4 f0 = *(const float4*)(W + (size_t)h * E_ + e0);
        float4 f1 = *(const float4*)(W + (size_t)h * E_ + e0 + 4);
        v[0] = (_Float16)f0.x; v[1] = (_Float16)f0.y;
        v[2] = (_Float16)f0.z; v[3] = (_Float16)f0.w;
        v[4] = (_Float16)f1.x; v[5] = (_Float16)f1.y;
        v[6] = (_Float16)f1.z; v[7] = (_Float16)f1.w;
    } else if (e0 < E_) {  // e0 = 296: last 4 real + 4 pad
        float4 f0 = *(const float4*)(W + (size_t)h * E_ + e0);
        v[0] = (_Float16)f0.x; v[1] = (_Float16)f0.y;
        v[2] = (_Float16)f0.z; v[3] = (_Float16)f0.w;
        v[4] = (_Float16)0.0f; v[5] = (_Float16)0.0f;
        v[6] = (_Float16)0.0f; v[7] = (_Float16)0.0f;
    } else {
        v = (h8_t)(_Float16)0.0f;
    }
    return v;
}

// ---------------------------------------------------------------------------
// Kernel B: xw[s,b,h] = sum_e emb[idx[s,b],e]*W_ih[h,e] + b_ih[h] + b_hh[h]
// MFMA, 512 blocks x 512 threads (8 waves). R7/R17/R19-validated, ~27us.
// ---------------------------------------------------------------------------
__global__ __launch_bounds__(512, 2) void xw_kernel(
    const int* __restrict__ idx, const float* __restrict__ emb,
    const float* __restrict__ W_ih, const float* __restrict__ b_ih,
    const float* __restrict__ b_hh, float* __restrict__ xw) {
    __shared__ uint4 Afrag[4 * 10 * 64];  // 40 KB
    const int tid = threadIdx.x;
    const int w = tid >> 6;  // wave 0..7
    const int l = tid & 63;
    const int n = l & 15;
    const int hi = l >> 4;
    const int base = blockIdx.x * 64;

    h8_t bw0[10], bw1[10];
#pragma unroll
    for (int ks = 0; ks < 10; ++ks) {
        bw0[ks] = load_wfrag(W_ih, (2 * w) * 16 + n, ks * 32 + hi * 8);
        bw1[ks] = load_wfrag(W_ih, (2 * w + 1) * 16 + n, ks * 32 + hi * 8);
    }
    const float bias0 = b_ih[w * 32 + n] + b_hh[w * 32 + n];
    const float bias1 = b_ih[w * 32 + 16 + n] + b_hh[w * 32 + 16 + n];

    for (int cc = tid; cc < 64 * 40; cc += 512) {
        int m = cc / 40;
        int c = cc - m * 40;  // chunk: e = 8c..8c+7
        int ks = c >> 2;
        int hic = c & 3;
        const float* src = emb + (size_t)idx[base + m] * E_ + 8 * c;
        h8_t v;
        if (c < 37) {
            float4 f0 = *(const float4*)src;
            float4 f1 = *(const float4*)(src + 4);
            v[0] = (_Float16)f0.x; v[1] = (_Float16)f0.y;
            v[2] = (_Float16)f0.z; v[3] = (_Float16)f0.w;
            v[4] = (_Float16)f1.x; v[5] = (_Float16)f1.y;
            v[6] = (_Float16)f1.z; v[7] = (_Float16)f1.w;
        } else if (c == 37) {
            float4 f0 = *(const float4*)src;
            v[0] = (_Float16)f0.x; v[1] = (_Float16)f0.y;
            v[2] = (_Float16)f0.z; v[3] = (_Float16)f0.w;
            v[4] = (_Float16)0.0f; v[5] = (_Float16)0.0f;
            v[6] = (_Float16)0.0f; v[7] = (_Float16)0.0f;
        } else {
            v = (h8_t)(_Float16)0.0f;
        }
        int fl = (hic << 4) | (m & 15);
        int mt = m >> 4;
        Afrag[(mt * 10 + ks) * 64 + fl] = __builtin_bit_cast(uint4, v);
    }
    __syncthreads();

    f32x4 c[4][2];
#pragma unroll
    for (int mt = 0; mt < 4; ++mt) {
        c[mt][0] = (f32x4)bias0;
        c[mt][1] = (f32x4)bias1;
    }
#pragma unroll
    for (int ks = 0; ks < 10; ++ks) {
#pragma unroll
        for (int mt = 0; mt < 4; ++mt) {
            h8_t a = __builtin_bit_cast(h8_t, Afrag[(mt * 10 + ks) * 64 + l]);
            c[mt][0] = __builtin_amdgcn_mfma_f32_16x16x32_f16(a, bw0[ks],
                                                              c[mt][0], 0, 0, 0);
            c[mt][1] = __builtin_amdgcn_mfma_f32_16x16x32_f16(a, bw1[ks],
                                                              c[mt][1], 0, 0, 0);
        }
    }
#pragma unroll
    for (int mt = 0; mt < 4; ++mt)
#pragma unroll
        for (int q = 0; q < 2; ++q) {
            float* op =
                xw + (size_t)(base + mt * 16 + hi * 4) * H_ + w * 32 + q * 16 + n;
#pragma unroll
            for (int r = 0; r < 4; ++r) op[(size_t)r * H_] = c[mt][q][r];
        }
}

// ---------------------------------------------------------------------------
// Kernel C: MFMA recurrence, 16-WAVE x 16-ROW topology, BROADCAST-4.
// 16 blocks x 4 batch cols, 1024 threads (16 waves, 1 block/CU,
// 4 waves/SIMD — double R14's TLP, the one unmapped axis).
//
// Rationale: R14/R15/R19 mapped the 2-waves/SIMD space; step = 1090cyc with
// no pipe >50% — residual is per-wave chain latency under 2-way interleave.
// rows/wave = 16 makes A = 32 regs, so 4 waves/SIMD fits the 128-reg budget
// (prior TLP attempts died of spill at A=128). Per-CU MFMA/step unchanged
// (128); per-wave: 8 ds_read_b128 (256B unique each — lane quads n,n+4,n+8,
// n+12 same addr, <=2 addr/bank = free), 8-deep MFMA chain, 1 tanh, 1 b16
// write (4-way dup split: lane handles C component d = n>>2).
//
//   Per-buffer LDS layout (2KB), col c in 0..3, k in 0..255:
//     byte(k,c) = (k>>5)*256 + ((k>>3)&3)*64 + c*16 + (k&7)*2
//   read:  lane l (n=l&15, hi=l>>4), slice ks ->
//          b128 at ks*256 + hi*64 + (n&3)*16
//   write: lane (w,hi,n): row k0 = w*16 + hi*4 + (n>>2), col n&3 ->
//          b16 at (k0>>5)*256 + ((k0>>3)&3)*64 + (n&3)*16 + (k0&7)*2
//   Light barrier (lgkmcnt only) + distance-2 xw prefetch, 4-slot rotation.
//   Fused output epilogue: hsum (1 f32/lane) staged to dead H LDS
//   (bijective: 1024 lanes <-> 256 rows x 4 cols), wave w<4 computes batch
//   col bbase+w's logits + log_softmax.
// ---------------------------------------------------------------------------
__global__ __launch_bounds__(1024, 4) void rnn_kernel(
    const float* __restrict__ xw, const float* __restrict__ W_hh,
    const float* __restrict__ W_out, const float* __restrict__ b_out,
    float* __restrict__ out) {
    const int tid = threadIdx.x;
    const int w = tid >> 6;  // wave 0..15, rows 16w..16w+15
    const int l = tid & 63;
    const int n = l & 15;    // A row / B col / C col (0..15)
    const int hi = l >> 4;   // k-group
    const int col = n & 3;   // real batch col within block
    const int d = n >> 2;    // duplicate index 0..3 (epilogue split)
    const int bbase = blockIdx.x * 4;

    __shared__ __attribute__((aligned(16))) unsigned char smem[4096];
    char* lds = (char*)smem;  // [2][2048] H double-buffer

    // ---- A fragments: W_hh rows 16w..16w+15 as f16 (32 regs) ----
    h8_t a[8];
    {
        const float* wr = W_hh + (size_t)(w * 16 + n) * H_;
#pragma unroll
        for (int ks = 0; ks < 8; ++ks) {
            const float* wp = wr + ks * 32 + hi * 8;
            float4 f0 = *(const float4*)wp;
            float4 f1 = *(const float4*)(wp + 4);
            h8_t v;
            v[0] = (_Float16)f0.x; v[1] = (_Float16)f0.y;
            v[2] = (_Float16)f0.z; v[3] = (_Float16)f0.w;
            v[4] = (_Float16)f1.x; v[5] = (_Float16)f1.y;
            v[6] = (_Float16)f1.z; v[7] = (_Float16)f1.w;
            a[ks] = v;
        }
    }

    // H'-write: row k0 = w*16 + hi*4 + d, col (b16)
    const int k0 = w * 16 + hi * 4 + d;
    const int wboff =
        (k0 >> 5) * 256 + ((k0 >> 3) & 3) * 64 + col * 16 + (k0 & 7) * 2;
    // B-read base (buffer-relative); bf[ks] at CUR*2048 + rdbase + ks*256
    const int rdbase = hi * 64 + col * 16;

    // zero H buffer 0 (2 KB = 512 dwords)
    if (tid < 512) ((unsigned int*)lds)[tid] = 0u;

    float hs = 0.0f;  // running sum for this lane's (row k0, col)

    // per-lane xw base: xw[s][bbase+col][w*16 + hi*4 + r]
    const float* xwl = xw + (size_t)(bbase + col) * H_ + w * 16 + hi * 4;
    // 4-slot rotation of xw-as-C-operand buffers (distance-2 prefetch)
    f32x4 cv[4];
    cv[0] = *(const f32x4*)(xwl);          // s = 0
    cv[1] = *(const f32x4*)(xwl + 16384);  // s = 1
    __syncthreads();  // zero-init visible

#define STEP(CUR, I, SBASE)                                                    \
    {                                                                          \
        int sp = (SBASE) + 2;                                                  \
        if (sp > S_ - 1) sp = S_ - 1;                                          \
        cv[(I + 2) & 3] = *(const f32x4*)(xwl + (size_t)sp * 16384);           \
        h8_t bf[8];                                                            \
        _Pragma("unroll") for (int ks = 0; ks < 8; ++ks)                       \
            bf[ks] = *(const h8_t*)(lds + (CUR)*2048 + rdbase + ks * 256);     \
        _Pragma("unroll") for (int ks = 0; ks < 8; ++ks) {                     \
            cv[I] = __builtin_amdgcn_mfma_f32_16x16x32_f16(a[ks], bf[ks],      \
                                                           cv[I], 0, 0, 0);    \
        }                                                                      \
        {                                                                      \
            f32x4 sv = cv[I];                                                  \
            float e0 = (d == 1) ? sv[1] : sv[0];                               \
            e0 = (d == 2) ? sv[2] : e0;                                        \
            e0 = (d == 3) ? sv[3] : e0;                                        \
            float h0 = fast_tanh(e0);                                          \
            hs += h0;                                                          \
            *(unsigned short*)(lds + ((CUR) ^ 1) * 2048 + wboff) =             \
                __builtin_bit_cast(unsigned short, (_Float16)h0);              \
        }                                                                      \
        asm volatile("s_waitcnt lgkmcnt(0)" ::: "memory");                     \
        __builtin_amdgcn_s_barrier();                                          \
    }

    for (int s = 0; s < S_; s += 4) {
        STEP(0, 0, s)
        STEP(1, 1, s + 1)
        STEP(0, 2, s + 2)
        STEP(1, 3, s + 3)
    }
#undef STEP

    // ---- fused output epilogue: logits + log_softmax for cols bbase..+3 ----
    // Stage hs into the (dead) H LDS as f32 [col][k]: 4 cols x 256 = 4KB.
    // Bijective: lane (w,hi,n) -> (row k0, col).
    __syncthreads();  // all steps' LDS traffic done before repurposing
    *(float*)(lds + col * 1024 + k0 * 4) = hs;
    __syncthreads();
    if (w < 4) {  // wave w handles batch element bbase + w
        const float* hrow = (const float*)(lds + w * 1024);
        float lg[C_];
#pragma unroll
        for (int c = 0; c < C_; ++c) {
            float p = 0.0f;
#pragma unroll
            for (int q = 0; q < 4; ++q)
                p = fmaf(hrow[l + 64 * q], W_out[c * H_ + l + 64 * q], p);
#pragma unroll
            for (int off = 32; off; off >>= 1) p += __shfl_xor(p, off);
            lg[c] = p + (float)S_ * b_out[c];
        }
        if (l == 0) {
            float m = lg[0];
#pragma unroll
            for (int c = 1; c < C_; ++c) m = fmaxf(m, lg[c]);
            float sum = 0.0f;
#pragma unroll
            for (int c = 0; c < C_; ++c) sum += expf(lg[c] - m);
            float lse = logf(sum);
#pragma unroll
            for (int c = 0; c < C_; ++c)
                out[(bbase + w) * C_ + c] = lg[c] - m - lse;
        }
    }
}

// ---------------------------------------------------------------------------
extern "C" void kernel_launch(void* const* d_in, const int* in_sizes, int n_in,
                              void* d_out, int out_size, void* d_ws,
                              size_t ws_size, hipStream_t stream) {
    const int* idx = (const int*)d_in[0];
    const float* emb = (const float*)d_in[1];
    const float* W_ih = (const float*)d_in[2];
    const float* W_hh = (const float*)d_in[3];
    const float* b_ih = (const float*)d_in[4];
    const float* b_hh = (const float*)d_in[5];
    const float* W_out = (const float*)d_in[6];
    const float* b_out = (const float*)d_in[7];
    float* out = (float*)d_out;

    float* xw = (float*)d_ws;  // S*B*H floats

    hipLaunchKernelGGL(xw_kernel, dim3((S_ * B_) / 64), dim3(512), 0, stream,
                       idx, emb, W_ih, b_ih, b_hh, xw);
    hipLaunchKernelGGL(rnn_kernel, dim3(16), dim3(1024), 0, stream, xw, W_hh,
                       W_out, b_out, out);
}